// Round 13
// baseline (1357.696 us; speedup 1.0000x reference)
//
#include <hip/hip_runtime.h>

#define S_LEN 2048
#define B_SZ  64
#define D_IN  128
#define H_SZ  128
#define G4    512   // 4*H

typedef __attribute__((ext_vector_type(4))) float     floatx4;
typedef __attribute__((ext_vector_type(8))) _Float16  half8;
typedef __attribute__((ext_vector_type(4))) _Float16  half4;
typedef __attribute__((ext_vector_type(2))) _Float16  half2_t;

// DPP quad_perm helper (VALU pipe). CTRL: xor1=0xB1, xor2=0x4E.
template<int CTRL>
__device__ __forceinline__ float qperm(float v) {
  return __int_as_float(
      __builtin_amdgcn_mov_dpp(__float_as_int(v), CTRL, 0xF, 0xF, true));
}

template<int P>
__device__ __forceinline__ half2_t h2ext(half8 v) {
  return __builtin_shufflevector(v, v, 2 * P, 2 * P + 1);
}

// Barrier draining ONLY lgkmcnt (LDS); global loads/stores stay in flight.
__device__ __forceinline__ void lds_barrier() {
  asm volatile("s_waitcnt lgkmcnt(0)\n\ts_barrier" ::: "memory");
}

__device__ __forceinline__ float fd(half2_t a, half2_t b, float c) {
  return __builtin_amdgcn_fdot2(a, b, c, false);
}

__device__ __forceinline__ half8 wcvt(const float* __restrict__ p, float sc) {
  floatx4 v0 = *(const floatx4*)p;
  floatx4 v1 = *(const floatx4*)(p + 4);
  half8 h;
  h[0] = (_Float16)(v0.x * sc); h[1] = (_Float16)(v0.y * sc);
  h[2] = (_Float16)(v0.z * sc); h[3] = (_Float16)(v0.w * sc);
  h[4] = (_Float16)(v1.x * sc); h[5] = (_Float16)(v1.y * sc);
  h[6] = (_Float16)(v1.z * sc); h[7] = (_Float16)(v1.w * sc);
  return h;
}

// Cross-WG chunk-ready flags (zeroed per launch by hipMemsetAsync).
__device__ int g_flags[512];   // [b][chunk] = b*8 + chunk

// Shared-memory union: gx role needs Wl (34.8KB); lstm role needs 8.7KB.
union SharedU {
  _Float16 Wl[128][136];
  struct {
    _Float16 hbuf[2][H_SZ];
    float    tml[S_LEN];
  } l;
};

// ---------------------------------------------------------------------------
// ROUND 13: fused producer-consumer. During lstm (1113us) 192+ CUs idled
// while gx's 160us ran serially before it. lstm consumes gx in DESCENDING
// t; producers deliver 256-t chunks descending; consumer spin-waits on
// device-scope flags (guide G16: threadfence + device atomics). Deadlock-
// free by capacity: waves_per_eu(2,2) => 1 WG/CU => 64 lstm WGs occupy <=64
// CUs, producers always schedulable; worst-case scheduling degenerates to
// the old sequential time, never a hang.
// ---------------------------------------------------------------------------

// ---- producer: verified R6 gx body, one WG per batch, chunks 7..0 -------
__device__ void gx_role(int b, const float* __restrict__ X,
                        const float* __restrict__ Wih,
                        const float* __restrict__ bias,
                        _Float16* __restrict__ gx,
                        SharedU* su, int* __restrict__ flags)
{
  const int tid  = threadIdx.x;        // 0..511; compute waves: 0..3
  const int lane = tid & 63;
  const int wv   = tid >> 6;
  const int m    = lane & 15;
  const int q    = lane >> 4;
  const float LOG2E = 1.4426950408889634f;

  for (int chunk = 7; chunk >= 0; --chunk) {
    const int T0 = chunk * 256;

    half8 afrag[4][4];
    if (wv < 4) {
      #pragma unroll
      for (int rg = 0; rg < 4; ++rg) {
        const int t = T0 + rg * 64 + wv * 16 + m;
        const float* xrow = X + ((size_t)t * B_SZ + b) * D_IN;
        #pragma unroll
        for (int kf = 0; kf < 4; ++kf) {
          const int k0 = kf * 32 + q * 8;
          floatx4 v0 = *(const floatx4*)(xrow + k0);
          floatx4 v1 = *(const floatx4*)(xrow + k0 + 4);
          half8 a;
          a[0] = (_Float16)v0.x; a[1] = (_Float16)v0.y;
          a[2] = (_Float16)v0.z; a[3] = (_Float16)v0.w;
          a[4] = (_Float16)v1.x; a[5] = (_Float16)v1.y;
          a[6] = (_Float16)v1.z; a[7] = (_Float16)v1.w;
          afrag[rg][kf] = a;
        }
      }
    }

    for (int nc = 0; nc < 4; ++nc) {
      const float sc = (nc == 2) ? (-2.0f * LOG2E) : (-LOG2E);
      __syncthreads();
      for (int i = tid; i < 128 * 32; i += 512) {
        const int row = i >> 5;
        const int c4  = (i & 31) * 4;
        floatx4 v =
            *(const floatx4*)(Wih + ((size_t)nc * 128 + row) * D_IN + c4);
        su->Wl[row][c4 + 0] = (_Float16)v.x;
        su->Wl[row][c4 + 1] = (_Float16)v.y;
        su->Wl[row][c4 + 2] = (_Float16)v.z;
        su->Wl[row][c4 + 3] = (_Float16)v.w;
      }
      __syncthreads();

      if (wv < 4) {
        #pragma unroll
        for (int nt = 0; nt < 8; ++nt) {
          const int n0  = nc * 128 + nt * 16;
          const int nlo = nt * 16 + m;
          const float bv = bias[n0 + m];
          half8 bfrag[4];
          #pragma unroll
          for (int kf = 0; kf < 4; ++kf)
            bfrag[kf] = *(const half8*)(&su->Wl[nlo][kf * 32 + q * 8]);
          #pragma unroll
          for (int rg = 0; rg < 4; ++rg) {
            floatx4 acc = {bv, bv, bv, bv};
            #pragma unroll
            for (int kf = 0; kf < 4; ++kf)
              acc = __builtin_amdgcn_mfma_f32_16x16x32_f16(
                  afrag[rg][kf], bfrag[kf], acc, 0, 0, 0);
            const int tbase = T0 + rg * 64 + wv * 16 + q * 4;
            half4 hv;
            hv[0] = (_Float16)(acc[0] * sc);
            hv[1] = (_Float16)(acc[1] * sc);
            hv[2] = (_Float16)(acc[2] * sc);
            hv[3] = (_Float16)(acc[3] * sc);
            *(half4*)(gx + ((size_t)b * G4 + n0 + m) * S_LEN + tbase) = hv;
          }
        }
      }
    }

    // Publish: stores -> agent fence (per-thread) -> barrier -> flag.
    __threadfence();
    __syncthreads();
    if (tid == 0) atomicAdd(&flags[(b << 3) + chunk], 1);
  }
}

// ---- consumer: byte-identical R11 lstm body + chunk gating ---------------
#define PIN_WEIGHTS()                                                         \
  asm volatile(""                                                             \
               : "+v"(w00), "+v"(w01), "+v"(w02), "+v"(w03),                  \
                 "+v"(w10), "+v"(w11), "+v"(w12), "+v"(w13),                  \
                 "+v"(w20), "+v"(w21), "+v"(w22), "+v"(w23),                  \
                 "+v"(w30), "+v"(w31), "+v"(w32), "+v"(w33),                  \
                 "+v"(wt), "+v"(bt))

#define DOT8(HV, WA, WB, WC, WD)                                              \
  {                                                                           \
    q0a = fd(h2ext<0>(HV), h2ext<0>(WA), q0a);                                \
    q1a = fd(h2ext<0>(HV), h2ext<0>(WB), q1a);                                \
    q2a = fd(h2ext<0>(HV), h2ext<0>(WC), q2a);                                \
    q3a = fd(h2ext<0>(HV), h2ext<0>(WD), q3a);                                \
    q0a = fd(h2ext<1>(HV), h2ext<1>(WA), q0a);                                \
    q1a = fd(h2ext<1>(HV), h2ext<1>(WB), q1a);                                \
    q2a = fd(h2ext<1>(HV), h2ext<1>(WC), q2a);                                \
    q3a = fd(h2ext<1>(HV), h2ext<1>(WD), q3a);                                \
    q0b = fd(h2ext<2>(HV), h2ext<2>(WA), q0b);                                \
    q1b = fd(h2ext<2>(HV), h2ext<2>(WB), q1b);                                \
    q2b = fd(h2ext<2>(HV), h2ext<2>(WC), q2b);                                \
    q3b = fd(h2ext<2>(HV), h2ext<2>(WD), q3b);                                \
    q0b = fd(h2ext<3>(HV), h2ext<3>(WA), q0b);                                \
    q1b = fd(h2ext<3>(HV), h2ext<3>(WB), q1b);                                \
    q2b = fd(h2ext<3>(HV), h2ext<3>(WC), q2b);                                \
    q3b = fd(h2ext<3>(HV), h2ext<3>(WD), q3b);                                \
  }

#define GATE(HR, GXV, TMV, CVAR, HVAR)                                        \
  {                                                                           \
    half8 hv0 = *(const half8*)((HR) + 0 * 32 + tt * 8);                      \
    half8 hv1 = *(const half8*)((HR) + 1 * 32 + tt * 8);                      \
    half8 hv2 = *(const half8*)((HR) + 2 * 32 + tt * 8);                      \
    half8 hv3 = *(const half8*)((HR) + 3 * 32 + tt * 8);                      \
    asm volatile("" : "+v"(hv0), "+v"(hv1), "+v"(hv2), "+v"(hv3));            \
    float q0a = 0.f, q0b = 0.f, q1a = 0.f, q1b = 0.f;                         \
    float q2a = 0.f, q2b = 0.f, q3a = 0.f, q3b = 0.f;                         \
    PIN_WEIGHTS();                                                            \
    DOT8(hv0, w00, w10, w20, w30);                                            \
    PIN_WEIGHTS();                                                            \
    DOT8(hv1, w01, w11, w21, w31);                                            \
    PIN_WEIGHTS();                                                            \
    DOT8(hv2, w02, w12, w22, w32);                                            \
    PIN_WEIGHTS();                                                            \
    DOT8(hv3, w03, w13, w23, w33);                                            \
    float a0 = q0a + q0b, a1 = q1a + q1b, a2 = q2a + q2b, a3 = q3a + q3b;     \
    a0 += qperm<0xB1>(a0); a1 += qperm<0xB1>(a1);                             \
    a2 += qperm<0xB1>(a2); a3 += qperm<0xB1>(a3);                             \
    a0 += qperm<0x4E>(a0); a1 += qperm<0x4E>(a1);                             \
    a2 += qperm<0x4E>(a2); a3 += qperm<0x4E>(a3);                             \
    float pre = (tt & 1) ? ((tt & 2) ? a3 : a1) : ((tt & 2) ? a2 : a0);       \
    pre += (GXV);  /* already scaled by -log2e (or -2log2e for g) */          \
    const float e  = __builtin_amdgcn_exp2f(pre);                             \
    const float v  = fmaf(am, __builtin_amdgcn_rcpf(1.0f + e), aa);           \
    float z = fmaf((TMV), wt, bt);           /* = -log2e*(t*w_t+b_t) */       \
    z = fminf(z, 0.0f);                      /* -log2e*relu(.) */             \
    const float d  = __builtin_amdgcn_exp2f(z);                               \
    const float p2 = qperm<0x4E>(v);                                          \
    const float fv = (tt == 1) ? v : p2;                                      \
    const float r  = odd ? fv * (d * (CVAR)) : v * p2;                        \
    const float cn = r + qperm<0xB1>(r);                                      \
    (CVAR) = cn;                                                              \
    const float e2 = __builtin_amdgcn_exp2f(-2.0f * LOG2E * cn);              \
    const float th = fmaf(2.0f, __builtin_amdgcn_rcpf(1.0f + e2), -1.0f);     \
    (HVAR) = v * th;                                                          \
  }

#define SUB(K, TMV, RP, WP)                                                   \
  {                                                                           \
    const float g0 = (float)cur8[K];                                          \
    float h0;                                                                 \
    GATE(&hbuf[RP][0], g0, (TMV), c, h0);                                     \
    if (tt == 3) {                                                            \
      hbuf[WP][col] = (_Float16)h0;                                           \
      const int tcur = blk * 8 + K;                                           \
      out[((size_t)tcur << 13) + bH + col] = h0;                              \
      if (tcur == 0) {                                                        \
        float* hf = out + (size_t)S_LEN * B_SZ * H_SZ;                        \
        hf[bH + col] = h0;                                                    \
        hf[(size_t)B_SZ * H_SZ + bH + col] = c;                               \
      }                                                                       \
    }                                                                         \
    lds_barrier();                                                            \
  }

// Spin on producer flag (tid0 only), then WG-wide barrier + acquire fence.
#define WAITCH(CH)                                                            \
  {                                                                           \
    if (tid == 0) {                                                           \
      while (atomicAdd(&flags[(b << 3) + (CH)], 0) == 0)                      \
        __builtin_amdgcn_s_sleep(2);                                          \
    }                                                                         \
    __syncthreads();                                                          \
    __threadfence();                                                          \
  }

__device__ void lstm_role(int b, const _Float16* __restrict__ gx,
                          const float* __restrict__ timep,
                          const float* __restrict__ Whh,
                          const float* __restrict__ w_tp,
                          const float* __restrict__ b_tp,
                          float* __restrict__ out,
                          SharedU* su, int* __restrict__ flags)
{
  _Float16 (*hbuf)[H_SZ] = su->l.hbuf;
  float* tml = su->l.tml;
  const int tid = threadIdx.x;
  const int tt  = tid & 3;
  const int col = tid >> 2;
  const int j   = tt * 128 + col;

  const float LOG2E = 1.4426950408889634f;

  // Stage this batch's time column into LDS (one-time, 4 loads/thread).
  #pragma unroll
  for (int k = 0; k < 4; ++k) {
    const int idx = tid + k * 512;
    tml[idx] = timep[(idx << 6) + b];
  }

  // Pre-scaled f16 weights in 16 NAMED registers: wTI = sc(T) *
  // W_hh[T*128+col][I*32+tt*8 .. +7].
  half8 w00, w01, w02, w03, w10, w11, w12, w13;
  half8 w20, w21, w22, w23, w30, w31, w32, w33;
  {
    const float s1 = -LOG2E, s2 = -2.0f * LOG2E;
    const float* r0 = Whh + (size_t)(0 * 128 + col) * H_SZ + tt * 8;
    const float* r1 = Whh + (size_t)(1 * 128 + col) * H_SZ + tt * 8;
    const float* r2 = Whh + (size_t)(2 * 128 + col) * H_SZ + tt * 8;
    const float* r3 = Whh + (size_t)(3 * 128 + col) * H_SZ + tt * 8;
    w00 = wcvt(r0 +  0, s1); w01 = wcvt(r0 + 32, s1);
    w02 = wcvt(r0 + 64, s1); w03 = wcvt(r0 + 96, s1);
    w10 = wcvt(r1 +  0, s1); w11 = wcvt(r1 + 32, s1);
    w12 = wcvt(r1 + 64, s1); w13 = wcvt(r1 + 96, s1);
    w20 = wcvt(r2 +  0, s2); w21 = wcvt(r2 + 32, s2);
    w22 = wcvt(r2 + 64, s2); w23 = wcvt(r2 + 96, s2);
    w30 = wcvt(r3 +  0, s1); w31 = wcvt(r3 + 32, s1);
    w32 = wcvt(r3 + 64, s1); w33 = wcvt(r3 + 96, s1);
  }

  float wt = -LOG2E * w_tp[col];
  float bt = -LOG2E * b_tp[col];
  const float am  = (tt == 2) ? 2.0f : 1.0f;
  const float aa  = (tt == 2) ? -1.0f : 0.0f;
  const bool  odd = (tt & 1) != 0;

  if (tid < 2 * H_SZ) ((_Float16*)hbuf)[tid] = (_Float16)0.0f;
  __syncthreads();

  // Gate chunk 7 before the first gx touch, then prefetch as in R11.
  int have = 7;
  WAITCH(7);

  const _Float16* gxr = gx + ((size_t)b * G4 + j) * S_LEN;
  const size_t bH = (size_t)b * H_SZ;

  half8 cur8 = *(const half8*)(gxr + 255 * 8);
  half8 nxt8 = *(const half8*)(gxr + 254 * 8);

  float c = 0.0f;

  for (int blk = 255; blk >= 0; --blk) {
    PIN_WEIGHTS();
    const int pfb  = (blk >= 2) ? blk - 2 : 0;
    const int need = pfb >> 5;
    if (need != have) { WAITCH(need); have = need; }
    half8 fut8 = *(const half8*)(gxr + pfb * 8);
    const floatx4 tmA = *(const floatx4*)(&tml[blk * 8 + 4]); // t = +4..+7
    const floatx4 tmB = *(const floatx4*)(&tml[blk * 8 + 0]); // t = +0..+3

    // 8 substeps: t = blk*8+7 down to blk*8 (ping-pong parity returns to 0)
    SUB(7, tmA.w, 0, 1)
    SUB(6, tmA.z, 1, 0)
    SUB(5, tmA.y, 0, 1)
    SUB(4, tmA.x, 1, 0)
    SUB(3, tmB.w, 0, 1)
    SUB(2, tmB.z, 1, 0)
    SUB(1, tmB.y, 0, 1)
    SUB(0, tmB.x, 1, 0)

    cur8 = nxt8;
    nxt8 = fut8;
  }
}

// ---------------------------------------------------------------------------
__global__ __launch_bounds__(512)
__attribute__((amdgpu_waves_per_eu(2, 2)))
void fused(const float* __restrict__ X,        // (S,B,D)
           const float* __restrict__ timep,    // (S,B,1)
           const float* __restrict__ Wih,      // (4H,D)
           const float* __restrict__ Whh,      // (4H,H)
           const float* __restrict__ bias,     // (4H,)
           const float* __restrict__ w_tp,     // (H,)
           const float* __restrict__ b_tp,     // (H,)
           _Float16* __restrict__ gx,          // [64][512][2048] ws
           int* __restrict__ flags,            // [64][8]
           float* __restrict__ out)
{
  __shared__ __align__(16) SharedU su;
  const int bx = blockIdx.x;
  if (bx < 64) {
    gx_role(bx, X, Wih, bias, gx, &su, flags);
  } else {
    lstm_role(bx - 64, gx, timep, Whh, w_tp, b_tp, out, &su, flags);
  }
}

// ---------------------------------------------------------------------------
extern "C" void kernel_launch(void* const* d_in, const int* in_sizes, int n_in,
                              void* d_out, int out_size, void* d_ws, size_t ws_size,
                              hipStream_t stream) {
  const float* input = (const float*)d_in[0];   // (S,B,D)
  const float* timep = (const float*)d_in[1];   // (S,B,1)
  const float* W_ih  = (const float*)d_in[2];   // (4H,D)
  const float* W_hh  = (const float*)d_in[3];   // (4H,H)
  const float* bias  = (const float*)d_in[4];   // (4H,)
  const float* w_t   = (const float*)d_in[5];   // (H,)
  const float* b_t   = (const float*)d_in[6];   // (H,)
  float* out = (float*)d_out;

  _Float16* gx = (_Float16*)d_ws;   // 64*512*2048*2 = 128 MiB, [b][n][t]

  static int* flags_ptr = nullptr;
  if (!flags_ptr)
    (void)hipGetSymbolAddress((void**)&flags_ptr, HIP_SYMBOL(g_flags));

  hipMemsetAsync(flags_ptr, 0, 512 * sizeof(int), stream);

  fused<<<dim3(128), dim3(512), 0, stream>>>(
      input, timep, W_ih, W_hh, bias, w_t, b_t, gx, flags_ptr, out);
}